// Round 10
// baseline (105.105 us; speedup 1.0000x reference)
//
#include <hip/hip_runtime.h>

// Linear interpolation: 8.4M samples vs 16384 sorted knots.
// R10: SINGLE kernel. Each block builds its own LDS state directly from
// xp/yp (no build kernel, no workspace round-trip):
//   - interleaved 8B records {f32 x, bitcast f32 (f16 y, f16 s)}  (131 KB)
//   - u16 bucket->lo table via race-free disjoint scatter         (32 KB)
//     (knot j serves buckets [bucket(xp[j])+1, bucket(xp[j+1])])
// Inner loop identical to R8/R9 (proven): 1 ds_read_u16 + 4 adjacent f32x2
// window reads + cndmask select + exec-masked rare tail walk.

#define NB 16256            // u16 table = 32512 B LDS
#define NKMAX 16384
#define PADR 4              // +INF pad records
#define NREC (NKMAX + PADR)

typedef float f32x4 __attribute__((ext_vector_type(4)));
typedef float f32x2 __attribute__((ext_vector_type(2)));

__device__ __forceinline__ int bucket_of(float v, float lo, float inv_w) {
    // Monotone in v (fp32); single shared definition -> consistent everywhere.
    return (int)((v - lo) * inv_w);
}

__device__ __forceinline__ float pack_ys_f(float y, float s) {
    _Float16 hy = (_Float16)y, hs = (_Float16)s;
    unsigned short uy = __builtin_bit_cast(unsigned short, hy);
    unsigned short us = __builtin_bit_cast(unsigned short, hs);
    unsigned u = (unsigned)uy | ((unsigned)us << 16);
    return __builtin_bit_cast(float, u);
}

__device__ __forceinline__ float lerp_ys(float dx, float ysf) {
    unsigned u = __builtin_bit_cast(unsigned, ysf);
    float hy = (float)__builtin_bit_cast(_Float16, (unsigned short)(u & 0xffffu));
    float hs = (float)__builtin_bit_cast(_Float16, (unsigned short)(u >> 16));
    return fmaf(dx, hs, hy);
}

__global__ __launch_bounds__(1024) void interp(
        const f32x4* __restrict__ xs4, const float* __restrict__ xp,
        const float* __restrict__ yp, f32x4* __restrict__ out4,
        int n4, int nk) {
    __shared__ __align__(16) float srec[NREC * 2];   // 131104 B
    __shared__ unsigned short sT[NB];                // 32512 B  (total 163616)

    float lo = xp[0];
    float inv_w = (float)NB / (xp[nk - 1] - lo);

    // ---- build records + init table (u16 stores only; TBAA-safe) ----
    for (int i = threadIdx.x; i < NREC; i += 1024) {
        float x, ys;
        if (i < nk) {
            float x1 = xp[i], y1 = yp[i];
            x = x1;
            float s = 0.0f;
            if (i < nk - 1) s = (yp[i + 1] - y1) / (xp[i + 1] - x1);
            ys = pack_ys_f(y1, s);
        } else {                      // pad: +INF knot, never selected
            x = __builtin_inff(); ys = 0.0f;
        }
        srec[2 * i] = x;
        srec[2 * i + 1] = ys;
    }
    for (int i = threadIdx.x; i < NB; i += 1024) sT[i] = 0;
    __syncthreads();

    // ---- race-free table scatter: knot j -> buckets (b(xp[j]), b(xp[j+1])] ----
    for (int j = threadIdx.x; j < nk - 1; j += 1024) {
        int b0 = bucket_of(xp[j], lo, inv_w);         // >= 0 (xp[j] >= lo)
        int b1 = bucket_of(xp[j + 1], lo, inv_w);
        if (b1 > NB - 1) b1 = NB - 1;
        for (int i = b0 + 1; i <= b1; i++) sT[i] = (unsigned short)j;
    }
    __syncthreads();

    const f32x2* sr2 = (const f32x2*)srec;

    int tid = blockIdx.x * blockDim.x + threadIdx.x;
    int T = gridDim.x * blockDim.x;

    auto process = [&](f32x4 xq) -> f32x4 {
        float x[4] = {xq.x, xq.y, xq.z, xq.w};
        int base[4];
        f32x2 r0[4], r1[4], r2[4], r3[4];
        #pragma unroll
        for (int k = 0; k < 4; k++) {
            int b = bucket_of(x[k], lo, inv_w);   // >= 0 since x >= xp[0]
            b = min(b, NB - 1);
            base[k] = (int)sT[b];
            r0[k] = sr2[base[k]];                 // adjacent pairs ->
            r1[k] = sr2[base[k] + 1];             //   2x ds_read2_b64
            r2[k] = sr2[base[k] + 2];
            r3[k] = sr2[base[k] + 3];
        }
        f32x4 res;
        #pragma unroll
        for (int k = 0; k < 4; k++) {
            float xk = x[k];
            float xi = r0[k].x, ys = r0[k].y;     // x_base <= xk guaranteed
            if (r1[k].x <= xk) { xi = r1[k].x; ys = r1[k].y; }
            if (r2[k].x <= xk) { xi = r2[k].x; ys = r2[k].y; }
            bool tail = (r3[k].x <= xk);
            if (tail) {
                // window exhausted (rare): linear walk, exec-masked
                int j = base[k] + 3;
                while (srec[2 * (j + 1)] <= xk) j++;
                xi = srec[2 * j]; ys = srec[2 * j + 1];
            }
            res[k] = lerp_ys(xk - xi, ys);
        }
        return res;
    };

    if (n4 == 8 * T) {
        // Exact shape: 8 stages/thread, depth-3 software pipeline.
        f32x4 buf[8];
        #pragma unroll
        for (int s = 0; s < 3; s++)
            buf[s] = __builtin_nontemporal_load(&xs4[tid + s * T]);
        #pragma unroll
        for (int s = 0; s < 8; s++) {
            if (s + 3 < 8)
                buf[s + 3] = __builtin_nontemporal_load(&xs4[tid + (s + 3) * T]);
            f32x4 res = process(buf[s]);
            __builtin_nontemporal_store(res, &out4[tid + s * T]);
        }
    } else {
        for (int t = tid; t < n4; t += T) {
            f32x4 xq = __builtin_nontemporal_load(&xs4[t]);
            f32x4 res = process(xq);
            __builtin_nontemporal_store(res, &out4[t]);
        }
    }
}

extern "C" void kernel_launch(void* const* d_in, const int* in_sizes, int n_in,
                              void* d_out, int out_size, void* d_ws, size_t ws_size,
                              hipStream_t stream) {
    const float* xs = (const float*)d_in[0];
    const float* xp = (const float*)d_in[1];
    const float* yp = (const float*)d_in[2];
    int ns = in_sizes[0];
    int nk = in_sizes[1];
    (void)d_ws; (void)ws_size;

    int n4 = ns / 4;
    interp<<<256, 1024, 0, stream>>>((const f32x4*)xs, xp, yp,
                                     (f32x4*)d_out, n4, nk);
}